// Round 8
// baseline (120.090 us; speedup 1.0000x reference)
//
#include <hip/hip_runtime.h>

constexpr int NC = 32;    // channels C
constexpr int NH = 8;     // heads
constexpr int NS = 128;   // s
constexpr int NI = 256;   // i (q rows)
constexpr int NJ = 256;   // j (kv rows)
constexpr float LN_EPS = 1e-5f;
constexpr float QSCALE = 0.17677669529663687f;   // C^-0.5
constexpr float LOG2E  = 1.4426950408889634f;

typedef __bf16 bf16x8 __attribute__((ext_vector_type(8)));
typedef __bf16 bf16x2 __attribute__((ext_vector_type(2)));
typedef float floatx4 __attribute__((ext_vector_type(4)));

__device__ __forceinline__ float fexp2(float x) {
#if __has_builtin(__builtin_amdgcn_exp2f)
    return __builtin_amdgcn_exp2f(x);
#else
    return exp2f(x);
#endif
}
__device__ __forceinline__ float frcp(float x) {
#if __has_builtin(__builtin_amdgcn_rcpf)
    return __builtin_amdgcn_rcpf(x);
#else
    return 1.0f / x;
#endif
}
// HW bf16 pack (v_cvt_pk_bf16_f32 on gfx950), RNE
__device__ __forceinline__ unsigned pk2c(float a, float b) {
    union { bf16x2 v; unsigned u; } c;
    c.v = bf16x2{(__bf16)a, (__bf16)b};
    return c.u;
}

// XOR-swizzled LDS offsets (shorts). Rows of 32 shorts (4 x 16B chunks):
// phys_chunk = chunk ^ ((row>>1)&3)  -> <=2-way banks on all b128 reads.
__device__ __forceinline__ int qkOff(int row, int chunk) {
    return row * 32 + ((chunk ^ ((row >> 1) & 3)) << 3);
}
// V^T rows of 256 shorts (32 chunks): phys_chunk = chunk ^ (c&7).
__device__ __forceinline__ int vOff(int c, int chunk) {
    return c * 256 + ((chunk ^ (c & 7)) << 3);
}
// 16x32 slab (per wave, per it), same swizzle family as qkOff.
__device__ __forceinline__ int pOff(int base, int row, int chunk) {
    return base + row * 32 + ((chunk ^ ((row >> 1) & 3)) << 3);
}

// ---------------------------------------------------------------------------
// Kernel 1 (merged): blocks 0..255   : pair bias -> fp32 MFMA-C-fragment layout
//                    blocks 256..271 : wq/wk/wv/wg fragment prep (bf16)
//                    blocks 272..275 : wo B-fragment prep (bf16)
// bias32 layout: off(h,i,j) = h*65536 + jc*8192 + w*2048 + (jt*4+it)*256 + l*4 + r
//   log2e folded in (exp2 path).
// ---------------------------------------------------------------------------
__global__ __launch_bounds__(256) void biasprep_kernel(
    const float* __restrict__ z, const float* __restrict__ lnb_s,
    const float* __restrict__ lnb_b, const float* __restrict__ wb,
    const float* __restrict__ wq, const float* __restrict__ wk,
    const float* __restrict__ wv, const float* __restrict__ wg,
    const float* __restrict__ wo,
    float* __restrict__ bias32, unsigned short* __restrict__ wprep,
    unsigned short* __restrict__ wofrag)
{
    const int b = blockIdx.x;
    const int t = threadIdx.x;
    if (b < 256) {
        // ---- bias: block = one i, threads = j. Coalesced z stage via LDS. ----
        __shared__ float zL[256 * 33];               // pitch 33: conflict-free rows
        const float4* src = (const float4*)(z + (size_t)b * NJ * NC);
#pragma unroll
        for (int k = 0; k < 8; ++k) {
            int idx = t + 256 * k;                   // float4 index
            float4 v = src[idx];
            int f = idx * 4;
            int j = f >> 5, c = f & 31;
            zL[j * 33 + c]     = v.x; zL[j * 33 + c + 1] = v.y;
            zL[j * 33 + c + 2] = v.z; zL[j * 33 + c + 3] = v.w;
        }
        __syncthreads();

        float x[NC];
#pragma unroll
        for (int c = 0; c < NC; ++c) x[c] = zL[t * 33 + c];
        float mu = 0.f;
#pragma unroll
        for (int c = 0; c < NC; ++c) mu += x[c];
        mu *= (1.0f / NC);
        float var = 0.f;
#pragma unroll
        for (int c = 0; c < NC; ++c) { float d = x[c] - mu; var += d * d; }
        var *= (1.0f / NC);
        float rs = rsqrtf(var + LN_EPS);
        float acc[NH];
#pragma unroll
        for (int h = 0; h < NH; ++h) acc[h] = 0.f;
#pragma unroll
        for (int c = 0; c < NC; ++c) {
            float xn = (x[c] - mu) * rs * lnb_s[c] + lnb_b[c];
#pragma unroll
            for (int h = 0; h < NH; ++h) acc[h] += xn * wb[c * NH + h];
        }
        const int i = b;
        const int w_ = i >> 6, it = (i >> 4) & 3, lm = i & 15;
        const int jc = t >> 5, jt = (t >> 4) & 1, lq = (t >> 2) & 3, r = t & 3;
        const int base = jc * 8192 + w_ * 2048 + (jt * 4 + it) * 256
                       + (lq * 16 + lm) * 4 + r;
#pragma unroll
        for (int h = 0; h < NH; ++h)
            bias32[h * 65536 + base] = acc[h] * LOG2E;
    } else if (b < 272) {
        // ---- QKVG weight fragments ----
        int g = (b - 256) * 256 + t;                 // 0..4095
        int p  = g >> 10;
        int h  = (g >> 7) & 7;
        int ct = (g >> 6) & 1;
        int l  = g & 63;
        const float* W = (p == 0) ? wq : (p == 1) ? wk : (p == 2) ? wv : wg;
        float scale = (p == 0) ? QSCALE * LOG2E : (p == 3) ? LOG2E : 1.0f;
        int col = 32 * h + 16 * ct + (l & 15);
        int r0  = 8 * (l >> 4);
        float v[8];
#pragma unroll
        for (int e = 0; e < 8; ++e) v[e] = W[(r0 + e) * 256 + col] * scale;
        uint4 u;
        u.x = pk2c(v[0], v[1]); u.y = pk2c(v[2], v[3]);
        u.z = pk2c(v[4], v[5]); u.w = pk2c(v[6], v[7]);
        *(uint4*)&wprep[g * 8] = u;
    } else {
        // ---- wo B-fragments ----
        int g = (b - 272) * 256 + t;                 // 0..1023
        int tile = g >> 6;                           // kt*2+nt
        int l = g & 63;
        int kt = tile >> 1, nt = tile & 1;
        int r0 = kt * 32 + 8 * (l >> 4);
        int col = nt * 16 + (l & 15);
        float v[8];
#pragma unroll
        for (int e = 0; e < 8; ++e) v[e] = wo[(r0 + e) * 32 + col];
        uint4 u;
        u.x = pk2c(v[0], v[1]); u.y = pk2c(v[2], v[3]);
        u.z = pk2c(v[4], v[5]); u.w = pk2c(v[6], v[7]);
        *(uint4*)&wofrag[g * 8] = u;
    }
}

// ---------------------------------------------------------------------------
// Kernel 2: all-MFMA fused attention. 48 KB LDS -> 3 blocks/CU.
// R8 (single variable vs R7): software-pipeline the j-loop by 1 iteration.
// R7 proved the bias-C global loads were the critical path; R7 still paid
// one full latency bubble per jc (Cre[0] consumed ~0 cycles after its load,
// Ka0 ~0 after its LDS read). Now: prologue loads jc=0's Cre/Ka/Va; each
// Cre[it] is re-loaded for jc+1 right after its QK MFMA consumes it (same
// registers, WAR handled by scheduler); next-jc Ka/Va LDS reads issue in
// phase B under the PV MFMAs. Load->use distance ~= one full iteration.
// LDS: KX (X -> Q^T -> K) 16K | Vt (V^T [c][j]) 16K | Pbuf 16K = 48 KB.
// ---------------------------------------------------------------------------
__global__ __launch_bounds__(256, 3) void attn_kernel(
    const float* __restrict__ m, const float* __restrict__ ln_s,
    const float* __restrict__ ln_b,
    const unsigned short* __restrict__ wprep,
    const float* __restrict__ bias32,
    unsigned short* __restrict__ attn16)
{
    __shared__ unsigned short KX[256 * 32];    // X -> Q^T -> K rows (qkOff)
    __shared__ unsigned short Vt[32 * 256];    // V^T [c][j] (vOff)
    __shared__ unsigned short Pbuf[4 * 2048];  // per-wave, per-it 16x32 slabs

    const int t = threadIdx.x;
    const int h = blockIdx.x & 7;
    const int s = blockIdx.x >> 3;
    const int l = t & 63, w = t >> 6;
    const int lm = l & 15, lq = l >> 4;
    const int ibase = w * 64;
    const int pwb = w * 2048;
    const floatx4 zero = {0.f, 0.f, 0.f, 0.f};

    // ---- Phase 1: LN(m[s][t]) -> KX row t (bf16, swizzled). Wave-private. ----
    {
        const float4* mr = (const float4*)(m + ((size_t)s * NI + t) * NC);
        float x[NC];
#pragma unroll
        for (int k = 0; k < 8; ++k) {
            float4 v = mr[k];
            x[4*k] = v.x; x[4*k+1] = v.y; x[4*k+2] = v.z; x[4*k+3] = v.w;
        }
        float mu = 0.f;
#pragma unroll
        for (int c = 0; c < NC; ++c) mu += x[c];
        mu *= (1.0f / NC);
        float var = 0.f;
#pragma unroll
        for (int c = 0; c < NC; ++c) { float d = x[c] - mu; var += d * d; }
        var *= (1.0f / NC);
        float rs = rsqrtf(var + LN_EPS);
#pragma unroll
        for (int k = 0; k < 4; ++k) {
            uint4 u;
            u.x = pk2c((x[8*k+0]-mu)*rs*ln_s[8*k+0]+ln_b[8*k+0],
                       (x[8*k+1]-mu)*rs*ln_s[8*k+1]+ln_b[8*k+1]);
            u.y = pk2c((x[8*k+2]-mu)*rs*ln_s[8*k+2]+ln_b[8*k+2],
                       (x[8*k+3]-mu)*rs*ln_s[8*k+3]+ln_b[8*k+3]);
            u.z = pk2c((x[8*k+4]-mu)*rs*ln_s[8*k+4]+ln_b[8*k+4],
                       (x[8*k+5]-mu)*rs*ln_s[8*k+5]+ln_b[8*k+5]);
            u.w = pk2c((x[8*k+6]-mu)*rs*ln_s[8*k+6]+ln_b[8*k+6],
                       (x[8*k+7]-mu)*rs*ln_s[8*k+7]+ln_b[8*k+7]);
            *(uint4*)&KX[qkOff(t, k)] = u;
        }
    }
    // no barrier: wave-private rows; DS pipe is in-order per wave

    // ---- Phase 2: MFMA projections. Gate deferred to epilogue. ----
    const unsigned short* wp = wprep + ((size_t)h * 128 + l) * 8;
    bf16x8 wfQ[2], wfK[2], wfV[2];
#pragma unroll
    for (int ct = 0; ct < 2; ++ct) {
        wfQ[ct] = *(const bf16x8*)&wp[(0 * 1024 + ct * 64) * 8];
        wfK[ct] = *(const bf16x8*)&wp[(1 * 1024 + ct * 64) * 8];
        wfV[ct] = *(const bf16x8*)&wp[(2 * 1024 + ct * 64) * 8];
    }
    bf16x8 Xb[4];                                 // retained for epilogue gate
#pragma unroll
    for (int it = 0; it < 4; ++it)
        Xb[it] = *(const bf16x8*)&KX[qkOff(ibase + it * 16 + lm, lq)];
    // KX (X) now dead for this wave -> reuse rows for Q^T

    // Q^T rows [i][c]  (D[c][i]: lane lm = i, regs = 4 consecutive c)
#pragma unroll
    for (int it = 0; it < 4; ++it)
#pragma unroll
        for (int ct = 0; ct < 2; ++ct) {
            floatx4 d = __builtin_amdgcn_mfma_f32_16x16x32_bf16(wfQ[ct], Xb[it], zero, 0, 0, 0);
            uint2 u; u.x = pk2c(d[0], d[1]); u.y = pk2c(d[2], d[3]);
            int row = ibase + it * 16 + lm;
            *(uint2*)&KX[qkOff(row, 2 * ct + (lq >> 1)) + (lq & 1) * 4] = u;
        }
    // Hoist own Q^T B-frags BEFORE K overwrites the same rows
    bf16x8 Qb[4];
#pragma unroll
    for (int it = 0; it < 4; ++it)
        Qb[it] = *(const bf16x8*)&KX[qkOff(ibase + it * 16 + lm, lq)];

    // K rows [j][c] -> KX (overwrite Q^T; own rows, in-order DS pipe)
#pragma unroll
    for (int it = 0; it < 4; ++it)
#pragma unroll
        for (int ct = 0; ct < 2; ++ct) {
            floatx4 d = __builtin_amdgcn_mfma_f32_16x16x32_bf16(wfK[ct], Xb[it], zero, 0, 0, 0);
            uint2 u; u.x = pk2c(d[0], d[1]); u.y = pk2c(d[2], d[3]);
            int row = ibase + it * 16 + lm;
            *(uint2*)&KX[qkOff(row, 2 * ct + (lq >> 1)) + (lq & 1) * 4] = u;
        }

    // V -> Vt [c][j]  (D[j][c']: lane lm = c', regs = 4 consecutive j)
#pragma unroll
    for (int jt = 0; jt < 4; ++jt)
#pragma unroll
        for (int ct = 0; ct < 2; ++ct) {
            floatx4 d = __builtin_amdgcn_mfma_f32_16x16x32_bf16(Xb[jt], wfV[ct], zero, 0, 0, 0);
            uint2 u; u.x = pk2c(d[0], d[1]); u.y = pk2c(d[2], d[3]);
            int c = ct * 16 + lm;
            int chunk = 8 * w + 2 * jt + (lq >> 1);
            *(uint2*)&Vt[vOff(c, chunk) + (lq & 1) * 4] = u;
        }

    __syncthreads();   // KX (K) / Vt visible to all waves (the only barrier)

    floatx4 accO[2][4];
#pragma unroll
    for (int ct = 0; ct < 2; ++ct)
#pragma unroll
        for (int it = 0; it < 4; ++it) accO[ct][it] = zero;
    float accLv[4] = {0.f, 0.f, 0.f, 0.f};        // denominator, VALU (lane = i)

    const float* bptr = bias32 + (size_t)h * 65536 + w * 2048 + l * 4;

    // ---- Phase 3: software-pipelined j-loop (1 iteration deep) ----
    // Prologue: jc=0 operands
    floatx4 Cre[4][2];
#pragma unroll
    for (int it = 0; it < 4; ++it) {
        Cre[it][0] = *(const floatx4*)(bptr + it * 256);
        Cre[it][1] = *(const floatx4*)(bptr + (4 + it) * 256);
    }
    bf16x8 Ka0 = *(const bf16x8*)&KX[qkOff(lm, lq)];
    bf16x8 Ka1 = *(const bf16x8*)&KX[qkOff(16 + lm, lq)];
    bf16x8 Va0 = *(const bf16x8*)&Vt[vOff(lm, lq)];
    bf16x8 Va1 = *(const bf16x8*)&Vt[vOff(16 + lm, lq)];

    for (int jc = 0; jc < 8; ++jc) {
        const int jn = (jc + 1) & 7;               // wrap: tail loads are benign
        const float* bjn = bptr + jn * 8192;

        // Phase A: QK + exp2 + pack + slab-write; re-load Cre for jc+1
        // immediately after each use (same regs -> zero VGPR growth).
#pragma unroll
        for (int it = 0; it < 4; ++it) {
            const int pb = pwb + it * 512;         // private slab per (wave,it)
            floatx4 S0 = __builtin_amdgcn_mfma_f32_16x16x32_bf16(Ka0, Qb[it], Cre[it][0], 0, 0, 0);
            floatx4 S1 = __builtin_amdgcn_mfma_f32_16x16x32_bf16(Ka1, Qb[it], Cre[it][1], 0, 0, 0);
            Cre[it][0] = *(const floatx4*)(bjn + it * 256);
            Cre[it][1] = *(const floatx4*)(bjn + (4 + it) * 256);
            float p0 = fexp2(S0[0]), p1 = fexp2(S0[1]);
            float p2 = fexp2(S0[2]), p3 = fexp2(S0[3]);
            float p4 = fexp2(S1[0]), p5 = fexp2(S1[1]);
            float p6 = fexp2(S1[2]), p7 = fexp2(S1[3]);
            accLv[it] += ((p0 + p1) + (p2 + p3)) + ((p4 + p5) + (p6 + p7));
            uint2 u0; u0.x = pk2c(p0, p1); u0.y = pk2c(p2, p3);
            uint2 u1; u1.x = pk2c(p4, p5); u1.y = pk2c(p6, p7);
            // j = 16*jt + 4*lq + r -> chunk = 2*jt + (lq>>1), off (lq&1)*4
            *(uint2*)&Pbuf[pOff(pb, lm, 0 + (lq >> 1)) + (lq & 1) * 4] = u0;
            *(uint2*)&Pbuf[pOff(pb, lm, 2 + (lq >> 1)) + (lq & 1) * 4] = u1;
        }

        // Phase B: batched slab-reads, next-jc K/V prefetch, then PV MFMAs
        bf16x8 Pb0 = *(const bf16x8*)&Pbuf[pOff(pwb + 0 * 512, lm, lq)];
        bf16x8 Pb1 = *(const bf16x8*)&Pbuf[pOff(pwb + 1 * 512, lm, lq)];
        bf16x8 Pb2 = *(const bf16x8*)&Pbuf[pOff(pwb + 2 * 512, lm, lq)];
        bf16x8 Pb3 = *(const bf16x8*)&Pbuf[pOff(pwb + 3 * 512, lm, lq)];
        bf16x8 nKa0 = *(const bf16x8*)&KX[qkOff(jn * 32 + lm, lq)];
        bf16x8 nKa1 = *(const bf16x8*)&KX[qkOff(jn * 32 + 16 + lm, lq)];
        bf16x8 nVa0 = *(const bf16x8*)&Vt[vOff(lm, 4 * jn + lq)];
        bf16x8 nVa1 = *(const bf16x8*)&Vt[vOff(16 + lm, 4 * jn + lq)];
        accO[0][0] = __builtin_amdgcn_mfma_f32_16x16x32_bf16(Va0, Pb0, accO[0][0], 0, 0, 0);
        accO[1][0] = __builtin_amdgcn_mfma_f32_16x16x32_bf16(Va1, Pb0, accO[1][0], 0, 0, 0);
        accO[0][1] = __builtin_amdgcn_mfma_f32_16x16x32_bf16(Va0, Pb1, accO[0][1], 0, 0, 0);
        accO[1][1] = __builtin_amdgcn_mfma_f32_16x16x32_bf16(Va1, Pb1, accO[1][1], 0, 0, 0);
        accO[0][2] = __builtin_amdgcn_mfma_f32_16x16x32_bf16(Va0, Pb2, accO[0][2], 0, 0, 0);
        accO[1][2] = __builtin_amdgcn_mfma_f32_16x16x32_bf16(Va1, Pb2, accO[1][2], 0, 0, 0);
        accO[0][3] = __builtin_amdgcn_mfma_f32_16x16x32_bf16(Va0, Pb3, accO[0][3], 0, 0, 0);
        accO[1][3] = __builtin_amdgcn_mfma_f32_16x16x32_bf16(Va1, Pb3, accO[1][3], 0, 0, 0);
        Ka0 = nKa0; Ka1 = nKa1; Va0 = nVa0; Va1 = nVa1;
    }

    // ---- Epilogue: reduce L over lq, gate from retained Xb, store ----
    // accO / gate orientation: lane lm = i, regs = c' (4*lq + r per ct).
    {
        bf16x8 wfG0 = *(const bf16x8*)&wp[(3 * 1024 + 0 * 64) * 8];
        bf16x8 wfG1 = *(const bf16x8*)&wp[(3 * 1024 + 1 * 64) * 8];
#pragma unroll
        for (int it = 0; it < 4; ++it) {
            float L = accLv[it];
            L += __shfl_xor(L, 16, 64);
            L += __shfl_xor(L, 32, 64);
            const float inv = frcp(L);               // L[i = ibase + it*16 + lm]
            floatx4 d0 = __builtin_amdgcn_mfma_f32_16x16x32_bf16(wfG0, Xb[it], zero, 0, 0, 0);
            floatx4 d1 = __builtin_amdgcn_mfma_f32_16x16x32_bf16(wfG1, Xb[it], zero, 0, 0, 0);
            const size_t rowb = ((size_t)s * NI + ibase + it * 16 + lm) * 256 + h * 32;
            {
                float o0 = accO[0][it][0] * inv * frcp(1.0f + fexp2(-d0[0]));
                float o1 = accO[0][it][1] * inv * frcp(1.0f + fexp2(-d0[1]));
                float o2 = accO[0][it][2] * inv * frcp(1.0f + fexp2(-d0[2]));
                float o3 = accO[0][it][3] * inv * frcp(1.0f + fexp2(-d0[3]));
                uint2 u; u.x = pk2c(o0, o1); u.y = pk2c(o2, o3);
                *(uint2*)&attn16[rowb + 0 * 16 + lq * 4] = u;
            }
            {
                float o0 = accO[1][it][0] * inv * frcp(1.0f + fexp2(-d1[0]));
                float o1 = accO[1][it][1] * inv * frcp(1.0f + fexp2(-d1[1]));
                float o2 = accO[1][it][2] * inv * frcp(1.0f + fexp2(-d1[2]));
                float o3 = accO[1][it][3] * inv * frcp(1.0f + fexp2(-d1[3]));
                uint2 u; u.x = pk2c(o0, o1); u.y = pk2c(o2, o3);
                *(uint2*)&attn16[rowb + 1 * 16 + lq * 4] = u;
            }
        }
    }
}

// ---------------------------------------------------------------------------
// Kernel 3: MFMA output projection. out = attn16(32768x256) @ wo(256x32) + bo
// ---------------------------------------------------------------------------
__global__ __launch_bounds__(256) void proj_kernel(
    const unsigned short* __restrict__ attn16,
    const unsigned short* __restrict__ wofrag,
    const float* __restrict__ bo, float* __restrict__ out)
{
    const int t = threadIdx.x;
    const int l = t & 63, w = t >> 6;
    const int lm = l & 15, lq = l >> 4;
    const int row0 = blockIdx.x * 128 + w * 32;
    const floatx4 zero = {0.f, 0.f, 0.f, 0.f};

    floatx4 acc[2][2];
#pragma unroll
    for (int it = 0; it < 2; ++it)
#pragma unroll
        for (int nt = 0; nt < 2; ++nt) acc[it][nt] = zero;

#pragma unroll 2
    for (int kt = 0; kt < 8; ++kt) {
        bf16x8 a0 = *(const bf16x8*)&attn16[(size_t)(row0 + lm) * 256 + kt * 32 + lq * 8];
        bf16x8 a1 = *(const bf16x8*)&attn16[(size_t)(row0 + 16 + lm) * 256 + kt * 32 + lq * 8];
        bf16x8 b0 = *(const bf16x8*)&wofrag[((kt * 2 + 0) * 64 + l) * 8];
        bf16x8 b1 = *(const bf16x8*)&wofrag[((kt * 2 + 1) * 64 + l) * 8];
        acc[0][0] = __builtin_amdgcn_mfma_f32_16x16x32_bf16(a0, b0, acc[0][0], 0, 0, 0);
        acc[0][1] = __builtin_amdgcn_mfma_f32_16x16x32_bf16(a0, b1, acc[0][1], 0, 0, 0);
        acc[1][0] = __builtin_amdgcn_mfma_f32_16x16x32_bf16(a1, b0, acc[1][0], 0, 0, 0);
        acc[1][1] = __builtin_amdgcn_mfma_f32_16x16x32_bf16(a1, b1, acc[1][1], 0, 0, 0);
    }

    float bov[2] = {bo[lm], bo[16 + lm]};
#pragma unroll
    for (int it = 0; it < 2; ++it)
#pragma unroll
        for (int nt = 0; nt < 2; ++nt)
#pragma unroll
            for (int r = 0; r < 4; ++r)
                out[(size_t)(row0 + it * 16 + lq * 4 + r) * NC + nt * 16 + lm]
                    = acc[it][nt][r] + bov[nt];
}

// ---------------------------------------------------------------------------
extern "C" void kernel_launch(void* const* d_in, const int* in_sizes, int n_in,
                              void* d_out, int out_size, void* d_ws, size_t ws_size,
                              hipStream_t stream) {
    const float* m     = (const float*)d_in[0];
    const float* z     = (const float*)d_in[1];
    const float* ln_s  = (const float*)d_in[2];
    const float* ln_b  = (const float*)d_in[3];
    const float* lnb_s = (const float*)d_in[4];
    const float* lnb_b = (const float*)d_in[5];
    const float* wq    = (const float*)d_in[6];
    const float* wk    = (const float*)d_in[7];
    const float* wv    = (const float*)d_in[8];
    const float* wb    = (const float*)d_in[9];
    const float* wg    = (const float*)d_in[10];
    const float* wo    = (const float*)d_in[11];
    const float* bo    = (const float*)d_in[12];
    float* out = (float*)d_out;

    // ws: bias32 2 MB | wprep 64 KB | wofrag 16 KB | attn16 16.78 MB
    float* bias32 = (float*)d_ws;
    unsigned short* wprep  = (unsigned short*)((char*)d_ws + (2u << 20));
    unsigned short* wofrag = (unsigned short*)((char*)d_ws + (2u << 20) + 65536);
    unsigned short* attn16 = (unsigned short*)((char*)d_ws + (2u << 20) + 65536 + 16384);

    biasprep_kernel<<<276, 256, 0, stream>>>(z, lnb_s, lnb_b, wb, wq, wk, wv, wg,
                                             wo, bias32, wprep, wofrag);
    attn_kernel<<<NS * NH, 256, 0, stream>>>(m, ln_s, ln_b, wprep, bias32, attn16);
    proj_kernel<<<(NS * NI) / 128, 256, 0, stream>>>(attn16, wofrag, bo, out);
}

// Round 9
// 118.340 us; speedup vs baseline: 1.0148x; 1.0148x over previous
//
#include <hip/hip_runtime.h>

constexpr int NC = 32;    // channels C
constexpr int NH = 8;     // heads
constexpr int NS = 128;   // s
constexpr int NI = 256;   // i (q rows)
constexpr int NJ = 256;   // j (kv rows)
constexpr float LN_EPS = 1e-5f;
constexpr float QSCALE = 0.17677669529663687f;   // C^-0.5
constexpr float LOG2E  = 1.4426950408889634f;

typedef __bf16 bf16x8 __attribute__((ext_vector_type(8)));
typedef __bf16 bf16x2 __attribute__((ext_vector_type(2)));
typedef float floatx4 __attribute__((ext_vector_type(4)));

__device__ __forceinline__ float fexp2(float x) {
#if __has_builtin(__builtin_amdgcn_exp2f)
    return __builtin_amdgcn_exp2f(x);
#else
    return exp2f(x);
#endif
}
__device__ __forceinline__ float frcp(float x) {
#if __has_builtin(__builtin_amdgcn_rcpf)
    return __builtin_amdgcn_rcpf(x);
#else
    return 1.0f / x;
#endif
}
// HW bf16 pack (v_cvt_pk_bf16_f32 on gfx950), RNE
__device__ __forceinline__ unsigned pk2c(float a, float b) {
    union { bf16x2 v; unsigned u; } c;
    c.v = bf16x2{(__bf16)a, (__bf16)b};
    return c.u;
}

// XOR-swizzled LDS offsets (shorts). Rows of 32 shorts (4 x 16B chunks):
// phys_chunk = chunk ^ ((row>>1)&3)  -> <=2-way banks on all b128 reads.
__device__ __forceinline__ int qkOff(int row, int chunk) {
    return row * 32 + ((chunk ^ ((row >> 1) & 3)) << 3);
}
// V^T rows of 256 shorts (32 chunks): phys_chunk = chunk ^ (c&7).
__device__ __forceinline__ int vOff(int c, int chunk) {
    return c * 256 + ((chunk ^ (c & 7)) << 3);
}
// 16x32 slab (per wave, per it), same swizzle family as qkOff.
__device__ __forceinline__ int pOff(int base, int row, int chunk) {
    return base + row * 32 + ((chunk ^ ((row >> 1) & 3)) << 3);
}

// ---------------------------------------------------------------------------
// Kernel 1 (merged): blocks 0..255   : pair bias -> fp32 MFMA-C-fragment layout
//                    blocks 256..271 : wq/wk/wv/wg fragment prep (bf16)
//                    blocks 272..275 : wo B-fragment prep (bf16)
// bias32 layout: off(h,i,j) = h*65536 + jc*8192 + w*2048 + (jt*4+it)*256 + l*4 + r
//   log2e folded in (exp2 path).
// ---------------------------------------------------------------------------
__global__ __launch_bounds__(256) void biasprep_kernel(
    const float* __restrict__ z, const float* __restrict__ lnb_s,
    const float* __restrict__ lnb_b, const float* __restrict__ wb,
    const float* __restrict__ wq, const float* __restrict__ wk,
    const float* __restrict__ wv, const float* __restrict__ wg,
    const float* __restrict__ wo,
    float* __restrict__ bias32, unsigned short* __restrict__ wprep,
    unsigned short* __restrict__ wofrag)
{
    const int b = blockIdx.x;
    const int t = threadIdx.x;
    if (b < 256) {
        // ---- bias: block = one i, threads = j. Coalesced z stage via LDS. ----
        __shared__ float zL[256 * 33];               // pitch 33: conflict-free rows
        const float4* src = (const float4*)(z + (size_t)b * NJ * NC);
#pragma unroll
        for (int k = 0; k < 8; ++k) {
            int idx = t + 256 * k;                   // float4 index
            float4 v = src[idx];
            int f = idx * 4;
            int j = f >> 5, c = f & 31;
            zL[j * 33 + c]     = v.x; zL[j * 33 + c + 1] = v.y;
            zL[j * 33 + c + 2] = v.z; zL[j * 33 + c + 3] = v.w;
        }
        __syncthreads();

        float x[NC];
#pragma unroll
        for (int c = 0; c < NC; ++c) x[c] = zL[t * 33 + c];
        float mu = 0.f;
#pragma unroll
        for (int c = 0; c < NC; ++c) mu += x[c];
        mu *= (1.0f / NC);
        float var = 0.f;
#pragma unroll
        for (int c = 0; c < NC; ++c) { float d = x[c] - mu; var += d * d; }
        var *= (1.0f / NC);
        float rs = rsqrtf(var + LN_EPS);
        float acc[NH];
#pragma unroll
        for (int h = 0; h < NH; ++h) acc[h] = 0.f;
#pragma unroll
        for (int c = 0; c < NC; ++c) {
            float xn = (x[c] - mu) * rs * lnb_s[c] + lnb_b[c];
#pragma unroll
            for (int h = 0; h < NH; ++h) acc[h] += xn * wb[c * NH + h];
        }
        const int i = b;
        const int w_ = i >> 6, it = (i >> 4) & 3, lm = i & 15;
        const int jc = t >> 5, jt = (t >> 4) & 1, lq = (t >> 2) & 3, r = t & 3;
        const int base = jc * 8192 + w_ * 2048 + (jt * 4 + it) * 256
                       + (lq * 16 + lm) * 4 + r;
#pragma unroll
        for (int h = 0; h < NH; ++h)
            bias32[h * 65536 + base] = acc[h] * LOG2E;
    } else if (b < 272) {
        // ---- QKVG weight fragments ----
        int g = (b - 256) * 256 + t;                 // 0..4095
        int p  = g >> 10;
        int h  = (g >> 7) & 7;
        int ct = (g >> 6) & 1;
        int l  = g & 63;
        const float* W = (p == 0) ? wq : (p == 1) ? wk : (p == 2) ? wv : wg;
        float scale = (p == 0) ? QSCALE * LOG2E : (p == 3) ? LOG2E : 1.0f;
        int col = 32 * h + 16 * ct + (l & 15);
        int r0  = 8 * (l >> 4);
        float v[8];
#pragma unroll
        for (int e = 0; e < 8; ++e) v[e] = W[(r0 + e) * 256 + col] * scale;
        uint4 u;
        u.x = pk2c(v[0], v[1]); u.y = pk2c(v[2], v[3]);
        u.z = pk2c(v[4], v[5]); u.w = pk2c(v[6], v[7]);
        *(uint4*)&wprep[g * 8] = u;
    } else {
        // ---- wo B-fragments ----
        int g = (b - 272) * 256 + t;                 // 0..1023
        int tile = g >> 6;                           // kt*2+nt
        int l = g & 63;
        int kt = tile >> 1, nt = tile & 1;
        int r0 = kt * 32 + 8 * (l >> 4);
        int col = nt * 16 + (l & 15);
        float v[8];
#pragma unroll
        for (int e = 0; e < 8; ++e) v[e] = wo[(r0 + e) * 32 + col];
        uint4 u;
        u.x = pk2c(v[0], v[1]); u.y = pk2c(v[2], v[3]);
        u.z = pk2c(v[4], v[5]); u.w = pk2c(v[6], v[7]);
        *(uint4*)&wofrag[g * 8] = u;
    }
}

// ---------------------------------------------------------------------------
// Kernel 2: all-MFMA fused attention. 48 KB LDS -> 3 blocks/CU.
// j-loop = R7's proven schedule (bias-C batch prefetch + A/B phase split;
// R8's deeper pipeline was neutral and is reverted).
// R9 change: attn16 is stored in proj's A-FRAGMENT-LINEAR layout:
//   frag id = (globalrow>>4)*8 + (col>>5), offset (shorts) =
//   ((col>>3)&3)*128 + (row&15)*8 + (col&7).
// Epilogue uint2 stores become wave-contiguous 512B segments (was: 8B per
// lane at 512B stride = 64 L2 sectors per store); proj loads become 1KB
// fully-coalesced (was 64 sectors per load).
// LDS: KX (X -> Q^T -> K) 16K | Vt (V^T [c][j]) 16K | Pbuf 16K = 48 KB.
// ---------------------------------------------------------------------------
__global__ __launch_bounds__(256, 3) void attn_kernel(
    const float* __restrict__ m, const float* __restrict__ ln_s,
    const float* __restrict__ ln_b,
    const unsigned short* __restrict__ wprep,
    const float* __restrict__ bias32,
    unsigned short* __restrict__ attn16)
{
    __shared__ unsigned short KX[256 * 32];    // X -> Q^T -> K rows (qkOff)
    __shared__ unsigned short Vt[32 * 256];    // V^T [c][j] (vOff)
    __shared__ unsigned short Pbuf[4 * 2048];  // per-wave, per-it 16x32 slabs

    const int t = threadIdx.x;
    const int h = blockIdx.x & 7;
    const int s = blockIdx.x >> 3;
    const int l = t & 63, w = t >> 6;
    const int lm = l & 15, lq = l >> 4;
    const int ibase = w * 64;
    const int pwb = w * 2048;
    const floatx4 zero = {0.f, 0.f, 0.f, 0.f};

    // ---- Phase 1: LN(m[s][t]) -> KX row t (bf16, swizzled). Wave-private. ----
    {
        const float4* mr = (const float4*)(m + ((size_t)s * NI + t) * NC);
        float x[NC];
#pragma unroll
        for (int k = 0; k < 8; ++k) {
            float4 v = mr[k];
            x[4*k] = v.x; x[4*k+1] = v.y; x[4*k+2] = v.z; x[4*k+3] = v.w;
        }
        float mu = 0.f;
#pragma unroll
        for (int c = 0; c < NC; ++c) mu += x[c];
        mu *= (1.0f / NC);
        float var = 0.f;
#pragma unroll
        for (int c = 0; c < NC; ++c) { float d = x[c] - mu; var += d * d; }
        var *= (1.0f / NC);
        float rs = rsqrtf(var + LN_EPS);
#pragma unroll
        for (int k = 0; k < 4; ++k) {
            uint4 u;
            u.x = pk2c((x[8*k+0]-mu)*rs*ln_s[8*k+0]+ln_b[8*k+0],
                       (x[8*k+1]-mu)*rs*ln_s[8*k+1]+ln_b[8*k+1]);
            u.y = pk2c((x[8*k+2]-mu)*rs*ln_s[8*k+2]+ln_b[8*k+2],
                       (x[8*k+3]-mu)*rs*ln_s[8*k+3]+ln_b[8*k+3]);
            u.z = pk2c((x[8*k+4]-mu)*rs*ln_s[8*k+4]+ln_b[8*k+4],
                       (x[8*k+5]-mu)*rs*ln_s[8*k+5]+ln_b[8*k+5]);
            u.w = pk2c((x[8*k+6]-mu)*rs*ln_s[8*k+6]+ln_b[8*k+6],
                       (x[8*k+7]-mu)*rs*ln_s[8*k+7]+ln_b[8*k+7]);
            *(uint4*)&KX[qkOff(t, k)] = u;
        }
    }
    // no barrier: wave-private rows; DS pipe is in-order per wave

    // ---- Phase 2: MFMA projections. Gate deferred to epilogue. ----
    const unsigned short* wp = wprep + ((size_t)h * 128 + l) * 8;
    bf16x8 wfQ[2], wfK[2], wfV[2];
#pragma unroll
    for (int ct = 0; ct < 2; ++ct) {
        wfQ[ct] = *(const bf16x8*)&wp[(0 * 1024 + ct * 64) * 8];
        wfK[ct] = *(const bf16x8*)&wp[(1 * 1024 + ct * 64) * 8];
        wfV[ct] = *(const bf16x8*)&wp[(2 * 1024 + ct * 64) * 8];
    }
    bf16x8 Xb[4];                                 // retained for epilogue gate
#pragma unroll
    for (int it = 0; it < 4; ++it)
        Xb[it] = *(const bf16x8*)&KX[qkOff(ibase + it * 16 + lm, lq)];
    // KX (X) now dead for this wave -> reuse rows for Q^T

    // Q^T rows [i][c]  (D[c][i]: lane lm = i, regs = 4 consecutive c)
#pragma unroll
    for (int it = 0; it < 4; ++it)
#pragma unroll
        for (int ct = 0; ct < 2; ++ct) {
            floatx4 d = __builtin_amdgcn_mfma_f32_16x16x32_bf16(wfQ[ct], Xb[it], zero, 0, 0, 0);
            uint2 u; u.x = pk2c(d[0], d[1]); u.y = pk2c(d[2], d[3]);
            int row = ibase + it * 16 + lm;
            *(uint2*)&KX[qkOff(row, 2 * ct + (lq >> 1)) + (lq & 1) * 4] = u;
        }
    // Hoist own Q^T B-frags BEFORE K overwrites the same rows
    bf16x8 Qb[4];
#pragma unroll
    for (int it = 0; it < 4; ++it)
        Qb[it] = *(const bf16x8*)&KX[qkOff(ibase + it * 16 + lm, lq)];

    // K rows [j][c] -> KX (overwrite Q^T; own rows, in-order DS pipe)
#pragma unroll
    for (int it = 0; it < 4; ++it)
#pragma unroll
        for (int ct = 0; ct < 2; ++ct) {
            floatx4 d = __builtin_amdgcn_mfma_f32_16x16x32_bf16(wfK[ct], Xb[it], zero, 0, 0, 0);
            uint2 u; u.x = pk2c(d[0], d[1]); u.y = pk2c(d[2], d[3]);
            int row = ibase + it * 16 + lm;
            *(uint2*)&KX[qkOff(row, 2 * ct + (lq >> 1)) + (lq & 1) * 4] = u;
        }

    // V -> Vt [c][j]  (D[j][c']: lane lm = c', regs = 4 consecutive j)
#pragma unroll
    for (int jt = 0; jt < 4; ++jt)
#pragma unroll
        for (int ct = 0; ct < 2; ++ct) {
            floatx4 d = __builtin_amdgcn_mfma_f32_16x16x32_bf16(Xb[jt], wfV[ct], zero, 0, 0, 0);
            uint2 u; u.x = pk2c(d[0], d[1]); u.y = pk2c(d[2], d[3]);
            int c = ct * 16 + lm;
            int chunk = 8 * w + 2 * jt + (lq >> 1);
            *(uint2*)&Vt[vOff(c, chunk) + (lq & 1) * 4] = u;
        }

    __syncthreads();   // KX (K) / Vt visible to all waves (the only barrier)

    floatx4 accO[2][4];
#pragma unroll
    for (int ct = 0; ct < 2; ++ct)
#pragma unroll
        for (int it = 0; it < 4; ++it) accO[ct][it] = zero;
    float accLv[4] = {0.f, 0.f, 0.f, 0.f};        // denominator, VALU (lane = i)

    const float* bptr = bias32 + (size_t)h * 65536 + w * 2048 + l * 4;

    // ---- Phase 3: j-loop, 32 j/iter; C prefetch + A/B phase split (R7) ----
    for (int jc = 0; jc < 8; ++jc) {
        const float* bj = bptr + jc * 8192;

        // hoisted bias C-loads: 8 x b128 issued back-to-back
        floatx4 Cre[4][2];
#pragma unroll
        for (int it = 0; it < 4; ++it) {
            Cre[it][0] = *(const floatx4*)(bj + it * 256);
            Cre[it][1] = *(const floatx4*)(bj + (4 + it) * 256);
        }
        bf16x8 Ka0 = *(const bf16x8*)&KX[qkOff(jc * 32 + lm, lq)];
        bf16x8 Ka1 = *(const bf16x8*)&KX[qkOff(jc * 32 + 16 + lm, lq)];
        bf16x8 Va0 = *(const bf16x8*)&Vt[vOff(lm, 4 * jc + lq)];
        bf16x8 Va1 = *(const bf16x8*)&Vt[vOff(16 + lm, 4 * jc + lq)];

        // Phase A: QK + exp2 + pack + slab-write, all 4 its
#pragma unroll
        for (int it = 0; it < 4; ++it) {
            const int pb = pwb + it * 512;         // private slab per (wave,it)
            floatx4 S0 = __builtin_amdgcn_mfma_f32_16x16x32_bf16(Ka0, Qb[it], Cre[it][0], 0, 0, 0);
            floatx4 S1 = __builtin_amdgcn_mfma_f32_16x16x32_bf16(Ka1, Qb[it], Cre[it][1], 0, 0, 0);
            float p0 = fexp2(S0[0]), p1 = fexp2(S0[1]);
            float p2 = fexp2(S0[2]), p3 = fexp2(S0[3]);
            float p4 = fexp2(S1[0]), p5 = fexp2(S1[1]);
            float p6 = fexp2(S1[2]), p7 = fexp2(S1[3]);
            accLv[it] += ((p0 + p1) + (p2 + p3)) + ((p4 + p5) + (p6 + p7));
            uint2 u0; u0.x = pk2c(p0, p1); u0.y = pk2c(p2, p3);
            uint2 u1; u1.x = pk2c(p4, p5); u1.y = pk2c(p6, p7);
            // j = 16*jt + 4*lq + r -> chunk = 2*jt + (lq>>1), off (lq&1)*4
            *(uint2*)&Pbuf[pOff(pb, lm, 0 + (lq >> 1)) + (lq & 1) * 4] = u0;
            *(uint2*)&Pbuf[pOff(pb, lm, 2 + (lq >> 1)) + (lq & 1) * 4] = u1;
        }

        // Phase B: batched slab-reads, then PV MFMAs
        bf16x8 Pb0 = *(const bf16x8*)&Pbuf[pOff(pwb + 0 * 512, lm, lq)];
        bf16x8 Pb1 = *(const bf16x8*)&Pbuf[pOff(pwb + 1 * 512, lm, lq)];
        bf16x8 Pb2 = *(const bf16x8*)&Pbuf[pOff(pwb + 2 * 512, lm, lq)];
        bf16x8 Pb3 = *(const bf16x8*)&Pbuf[pOff(pwb + 3 * 512, lm, lq)];
        accO[0][0] = __builtin_amdgcn_mfma_f32_16x16x32_bf16(Va0, Pb0, accO[0][0], 0, 0, 0);
        accO[1][0] = __builtin_amdgcn_mfma_f32_16x16x32_bf16(Va1, Pb0, accO[1][0], 0, 0, 0);
        accO[0][1] = __builtin_amdgcn_mfma_f32_16x16x32_bf16(Va0, Pb1, accO[0][1], 0, 0, 0);
        accO[1][1] = __builtin_amdgcn_mfma_f32_16x16x32_bf16(Va1, Pb1, accO[1][1], 0, 0, 0);
        accO[0][2] = __builtin_amdgcn_mfma_f32_16x16x32_bf16(Va0, Pb2, accO[0][2], 0, 0, 0);
        accO[1][2] = __builtin_amdgcn_mfma_f32_16x16x32_bf16(Va1, Pb2, accO[1][2], 0, 0, 0);
        accO[0][3] = __builtin_amdgcn_mfma_f32_16x16x32_bf16(Va0, Pb3, accO[0][3], 0, 0, 0);
        accO[1][3] = __builtin_amdgcn_mfma_f32_16x16x32_bf16(Va1, Pb3, accO[1][3], 0, 0, 0);
    }

    // ---- Epilogue: reduce L over lq, gate from retained Xb, store ----
    // accO / gate orientation: lane lm = i, regs = c' (4*lq + r per ct).
    // Store in frag-linear layout: frag = (globalrow>>4)*8 + head-col,
    // offset = (ct*2 + (lq>>1))*128 + lm*8 + (lq&1)*4 shorts.
    // Wave lanes cover a contiguous 512B segment per (it, ct).
    {
        bf16x8 wfG0 = *(const bf16x8*)&wp[(3 * 1024 + 0 * 64) * 8];
        bf16x8 wfG1 = *(const bf16x8*)&wp[(3 * 1024 + 1 * 64) * 8];
#pragma unroll
        for (int it = 0; it < 4; ++it) {
            float L = accLv[it];
            L += __shfl_xor(L, 16, 64);
            L += __shfl_xor(L, 32, 64);
            const float inv = frcp(L);               // L[i = ibase + it*16 + lm]
            floatx4 d0 = __builtin_amdgcn_mfma_f32_16x16x32_bf16(wfG0, Xb[it], zero, 0, 0, 0);
            floatx4 d1 = __builtin_amdgcn_mfma_f32_16x16x32_bf16(wfG1, Xb[it], zero, 0, 0, 0);
            const int tile16 = s * 16 + (w * 4 + it);   // globalrow >> 4
            unsigned short* ab = attn16 + ((size_t)(tile16 * 8 + h)) * 512;
            const int lo = lm * 8 + (lq & 1) * 4;
            {
                float o0 = accO[0][it][0] * inv * frcp(1.0f + fexp2(-d0[0]));
                float o1 = accO[0][it][1] * inv * frcp(1.0f + fexp2(-d0[1]));
                float o2 = accO[0][it][2] * inv * frcp(1.0f + fexp2(-d0[2]));
                float o3 = accO[0][it][3] * inv * frcp(1.0f + fexp2(-d0[3]));
                uint2 u; u.x = pk2c(o0, o1); u.y = pk2c(o2, o3);
                *(uint2*)&ab[(0 + (lq >> 1)) * 128 + lo] = u;
            }
            {
                float o0 = accO[1][it][0] * inv * frcp(1.0f + fexp2(-d1[0]));
                float o1 = accO[1][it][1] * inv * frcp(1.0f + fexp2(-d1[1]));
                float o2 = accO[1][it][2] * inv * frcp(1.0f + fexp2(-d1[2]));
                float o3 = accO[1][it][3] * inv * frcp(1.0f + fexp2(-d1[3]));
                uint2 u; u.x = pk2c(o0, o1); u.y = pk2c(o2, o3);
                *(uint2*)&ab[(2 + (lq >> 1)) * 128 + lo] = u;
            }
        }
    }
}

// ---------------------------------------------------------------------------
// Kernel 3: MFMA output projection. out = attn16(frag-linear) @ wo(256x32)+bo
// A-loads are now 1KB fully-coalesced frag reads (frag = tile16*8 + kt).
// ---------------------------------------------------------------------------
__global__ __launch_bounds__(256) void proj_kernel(
    const unsigned short* __restrict__ attn16,
    const unsigned short* __restrict__ wofrag,
    const float* __restrict__ bo, float* __restrict__ out)
{
    const int t = threadIdx.x;
    const int l = t & 63, w = t >> 6;
    const int lm = l & 15, lq = l >> 4;
    const int row0 = blockIdx.x * 128 + w * 32;
    const int t16 = row0 >> 4;                   // even tile16 index
    const floatx4 zero = {0.f, 0.f, 0.f, 0.f};

    floatx4 acc[2][2];
#pragma unroll
    for (int it = 0; it < 2; ++it)
#pragma unroll
        for (int nt = 0; nt < 2; ++nt) acc[it][nt] = zero;

#pragma unroll 2
    for (int kt = 0; kt < 8; ++kt) {
        bf16x8 a0 = *(const bf16x8*)&attn16[((size_t)((t16 + 0) * 8 + kt)) * 512 + l * 8];
        bf16x8 a1 = *(const bf16x8*)&attn16[((size_t)((t16 + 1) * 8 + kt)) * 512 + l * 8];
        bf16x8 b0 = *(const bf16x8*)&wofrag[((kt * 2 + 0) * 64 + l) * 8];
        bf16x8 b1 = *(const bf16x8*)&wofrag[((kt * 2 + 1) * 64 + l) * 8];
        acc[0][0] = __builtin_amdgcn_mfma_f32_16x16x32_bf16(a0, b0, acc[0][0], 0, 0, 0);
        acc[0][1] = __builtin_amdgcn_mfma_f32_16x16x32_bf16(a0, b1, acc[0][1], 0, 0, 0);
        acc[1][0] = __builtin_amdgcn_mfma_f32_16x16x32_bf16(a1, b0, acc[1][0], 0, 0, 0);
        acc[1][1] = __builtin_amdgcn_mfma_f32_16x16x32_bf16(a1, b1, acc[1][1], 0, 0, 0);
    }

    float bov[2] = {bo[lm], bo[16 + lm]};
#pragma unroll
    for (int it = 0; it < 2; ++it)
#pragma unroll
        for (int nt = 0; nt < 2; ++nt)
#pragma unroll
            for (int r = 0; r < 4; ++r)
                out[(size_t)(row0 + it * 16 + lq * 4 + r) * NC + nt * 16 + lm]
                    = acc[it][nt][r] + bov[nt];
}

// ---------------------------------------------------------------------------
extern "C" void kernel_launch(void* const* d_in, const int* in_sizes, int n_in,
                              void* d_out, int out_size, void* d_ws, size_t ws_size,
                              hipStream_t stream) {
    const float* m     = (const float*)d_in[0];
    const float* z     = (const float*)d_in[1];
    const float* ln_s  = (const float*)d_in[2];
    const float* ln_b  = (const float*)d_in[3];
    const float* lnb_s = (const float*)d_in[4];
    const float* lnb_b = (const float*)d_in[5];
    const float* wq    = (const float*)d_in[6];
    const float* wk    = (const float*)d_in[7];
    const float* wv    = (const float*)d_in[8];
    const float* wb    = (const float*)d_in[9];
    const float* wg    = (const float*)d_in[10];
    const float* wo    = (const float*)d_in[11];
    const float* bo    = (const float*)d_in[12];
    float* out = (float*)d_out;

    // ws: bias32 2 MB | wprep 64 KB | wofrag 16 KB | attn16 16.78 MB
    float* bias32 = (float*)d_ws;
    unsigned short* wprep  = (unsigned short*)((char*)d_ws + (2u << 20));
    unsigned short* wofrag = (unsigned short*)((char*)d_ws + (2u << 20) + 65536);
    unsigned short* attn16 = (unsigned short*)((char*)d_ws + (2u << 20) + 65536 + 16384);

    biasprep_kernel<<<276, 256, 0, stream>>>(z, lnb_s, lnb_b, wb, wq, wk, wv, wg,
                                             wo, bias32, wprep, wofrag);
    attn_kernel<<<NS * NH, 256, 0, stream>>>(m, ln_s, ln_b, wprep, bias32, attn16);
    proj_kernel<<<(NS * NI) / 128, 256, 0, stream>>>(attn16, wofrag, bo, out);
}

// Round 10
// 116.843 us; speedup vs baseline: 1.0278x; 1.0128x over previous
//
#include <hip/hip_runtime.h>

constexpr int NC = 32;    // channels C
constexpr int NH = 8;     // heads
constexpr int NS = 128;   // s
constexpr int NI = 256;   // i (q rows)
constexpr int NJ = 256;   // j (kv rows)
constexpr float LN_EPS = 1e-5f;
constexpr float QSCALE = 0.17677669529663687f;   // C^-0.5
constexpr float LOG2E  = 1.4426950408889634f;

typedef __bf16 bf16x8 __attribute__((ext_vector_type(8)));
typedef __bf16 bf16x2 __attribute__((ext_vector_type(2)));
typedef float floatx4 __attribute__((ext_vector_type(4)));

__device__ __forceinline__ float fexp2(float x) {
#if __has_builtin(__builtin_amdgcn_exp2f)
    return __builtin_amdgcn_exp2f(x);
#else
    return exp2f(x);
#endif
}
__device__ __forceinline__ float frcp(float x) {
#if __has_builtin(__builtin_amdgcn_rcpf)
    return __builtin_amdgcn_rcpf(x);
#else
    return 1.0f / x;
#endif
}
// HW bf16 pack (v_cvt_pk_bf16_f32 on gfx950), RNE
__device__ __forceinline__ unsigned pk2c(float a, float b) {
    union { bf16x2 v; unsigned u; } c;
    c.v = bf16x2{(__bf16)a, (__bf16)b};
    return c.u;
}

// XOR-swizzled LDS offsets (shorts). Rows of 32 shorts (4 x 16B chunks):
// phys_chunk = chunk ^ ((row>>1)&3)  -> <=2-way banks on all b128 reads.
__device__ __forceinline__ int qkOff(int row, int chunk) {
    return row * 32 + ((chunk ^ ((row >> 1) & 3)) << 3);
}
// V^T rows of 256 shorts (32 chunks): phys_chunk = chunk ^ (c&7).
__device__ __forceinline__ int vOff(int c, int chunk) {
    return c * 256 + ((chunk ^ (c & 7)) << 3);
}
// 16x32 slab (per wave, per it), same swizzle family as qkOff.
__device__ __forceinline__ int pOff(int base, int row, int chunk) {
    return base + row * 32 + ((chunk ^ ((row >> 1) & 3)) << 3);
}

// ---------------------------------------------------------------------------
// Kernel 1 (merged): blocks 0..255   : pair bias (REWRITTEN, R10)
//                    blocks 256..271 : wq/wk/wv/wg fragment prep (bf16)
//                    blocks 272..275 : wo B-fragment prep (bf16)
// R10 bias rewrite: the old version used 135 KB LDS (1 block/CU = 1 wave/
// SIMD, zero latency hiding), a barrier, and 8 fully-scattered 4B stores
// per thread. New: block = (16 i) x (16 j) tile == one 256-float contiguous
// bias32 chunk per head. Thread t IS the chunk offset: lm=(t>>2)&15 (i),
// lq=t>>6, r=t&3 (j); block b = w_*64 + it*16 + jc*2 + jt.
//   i = w_*64 + it*16 + lm ; j = jc*32 + jt*16 + lq*4 + r
//   store: bias32[h*65536 + jc*8192 + w_*2048 + (jt*4+it)*256 + t]
// -> per-wave stores are 256B contiguous; no LDS, no barrier; each thread
// reads its own dense 128B z row (8 independent float4 loads). Identical
// arithmetic order to R9 (bitwise-same bias values). log2e folded in.
// ---------------------------------------------------------------------------
__global__ __launch_bounds__(256) void biasprep_kernel(
    const float* __restrict__ z, const float* __restrict__ lnb_s,
    const float* __restrict__ lnb_b, const float* __restrict__ wb,
    const float* __restrict__ wq, const float* __restrict__ wk,
    const float* __restrict__ wv, const float* __restrict__ wg,
    const float* __restrict__ wo,
    float* __restrict__ bias32, unsigned short* __restrict__ wprep,
    unsigned short* __restrict__ wofrag)
{
    const int b = blockIdx.x;
    const int t = threadIdx.x;
    if (b < 256) {
        // ---- bias tile: b = w_*64 + it*16 + jc*2 + jt ----
        const int w_ = b >> 6;
        const int it = (b >> 4) & 3;
        const int jc = (b >> 1) & 7;
        const int jt = b & 1;
        const int lm = (t >> 2) & 15;          // i part
        const int lq = t >> 6, r = t & 3;      // j part
        const int i = w_ * 64 + it * 16 + lm;
        const int j = jc * 32 + jt * 16 + lq * 4 + r;

        // dense per-thread z row read: 8 independent float4 loads
        const float4* zr = (const float4*)(z + ((size_t)i * NJ + j) * NC);
        float x[NC];
#pragma unroll
        for (int k = 0; k < 8; ++k) {
            float4 v = zr[k];
            x[4*k] = v.x; x[4*k+1] = v.y; x[4*k+2] = v.z; x[4*k+3] = v.w;
        }
        float mu = 0.f;
#pragma unroll
        for (int c = 0; c < NC; ++c) mu += x[c];
        mu *= (1.0f / NC);
        float var = 0.f;
#pragma unroll
        for (int c = 0; c < NC; ++c) { float d = x[c] - mu; var += d * d; }
        var *= (1.0f / NC);
        float rs = rsqrtf(var + LN_EPS);
        float acc[NH];
#pragma unroll
        for (int h = 0; h < NH; ++h) acc[h] = 0.f;
#pragma unroll
        for (int c = 0; c < NC; ++c) {
            float xn = (x[c] - mu) * rs * lnb_s[c] + lnb_b[c];
#pragma unroll
            for (int h = 0; h < NH; ++h) acc[h] += xn * wb[c * NH + h];
        }
        const int base = jc * 8192 + w_ * 2048 + (jt * 4 + it) * 256 + t;
#pragma unroll
        for (int h = 0; h < NH; ++h)
            bias32[h * 65536 + base] = acc[h] * LOG2E;   // 256B/wave contiguous
    } else if (b < 272) {
        // ---- QKVG weight fragments ----
        int g = (b - 256) * 256 + t;                 // 0..4095
        int p  = g >> 10;
        int h  = (g >> 7) & 7;
        int ct = (g >> 6) & 1;
        int l  = g & 63;
        const float* W = (p == 0) ? wq : (p == 1) ? wk : (p == 2) ? wv : wg;
        float scale = (p == 0) ? QSCALE * LOG2E : (p == 3) ? LOG2E : 1.0f;
        int col = 32 * h + 16 * ct + (l & 15);
        int r0  = 8 * (l >> 4);
        float v[8];
#pragma unroll
        for (int e = 0; e < 8; ++e) v[e] = W[(r0 + e) * 256 + col] * scale;
        uint4 u;
        u.x = pk2c(v[0], v[1]); u.y = pk2c(v[2], v[3]);
        u.z = pk2c(v[4], v[5]); u.w = pk2c(v[6], v[7]);
        *(uint4*)&wprep[g * 8] = u;
    } else {
        // ---- wo B-fragments ----
        int g = (b - 272) * 256 + t;                 // 0..1023
        int tile = g >> 6;                           // kt*2+nt
        int l = g & 63;
        int kt = tile >> 1, nt = tile & 1;
        int r0 = kt * 32 + 8 * (l >> 4);
        int col = nt * 16 + (l & 15);
        float v[8];
#pragma unroll
        for (int e = 0; e < 8; ++e) v[e] = wo[(r0 + e) * 32 + col];
        uint4 u;
        u.x = pk2c(v[0], v[1]); u.y = pk2c(v[2], v[3]);
        u.z = pk2c(v[4], v[5]); u.w = pk2c(v[6], v[7]);
        *(uint4*)&wofrag[g * 8] = u;
    }
}

// ---------------------------------------------------------------------------
// Kernel 2: all-MFMA fused attention. 48 KB LDS -> 3 blocks/CU.
// j-loop = R7's proven schedule (bias-C batch prefetch + A/B phase split).
// attn16 stored in proj's A-fragment-linear layout (R9).
// LDS: KX (X -> Q^T -> K) 16K | Vt (V^T [c][j]) 16K | Pbuf 16K = 48 KB.
// ---------------------------------------------------------------------------
__global__ __launch_bounds__(256, 3) void attn_kernel(
    const float* __restrict__ m, const float* __restrict__ ln_s,
    const float* __restrict__ ln_b,
    const unsigned short* __restrict__ wprep,
    const float* __restrict__ bias32,
    unsigned short* __restrict__ attn16)
{
    __shared__ unsigned short KX[256 * 32];    // X -> Q^T -> K rows (qkOff)
    __shared__ unsigned short Vt[32 * 256];    // V^T [c][j] (vOff)
    __shared__ unsigned short Pbuf[4 * 2048];  // per-wave, per-it 16x32 slabs

    const int t = threadIdx.x;
    const int h = blockIdx.x & 7;
    const int s = blockIdx.x >> 3;
    const int l = t & 63, w = t >> 6;
    const int lm = l & 15, lq = l >> 4;
    const int ibase = w * 64;
    const int pwb = w * 2048;
    const floatx4 zero = {0.f, 0.f, 0.f, 0.f};

    // ---- Phase 1: LN(m[s][t]) -> KX row t (bf16, swizzled). Wave-private. ----
    {
        const float4* mr = (const float4*)(m + ((size_t)s * NI + t) * NC);
        float x[NC];
#pragma unroll
        for (int k = 0; k < 8; ++k) {
            float4 v = mr[k];
            x[4*k] = v.x; x[4*k+1] = v.y; x[4*k+2] = v.z; x[4*k+3] = v.w;
        }
        float mu = 0.f;
#pragma unroll
        for (int c = 0; c < NC; ++c) mu += x[c];
        mu *= (1.0f / NC);
        float var = 0.f;
#pragma unroll
        for (int c = 0; c < NC; ++c) { float d = x[c] - mu; var += d * d; }
        var *= (1.0f / NC);
        float rs = rsqrtf(var + LN_EPS);
#pragma unroll
        for (int k = 0; k < 4; ++k) {
            uint4 u;
            u.x = pk2c((x[8*k+0]-mu)*rs*ln_s[8*k+0]+ln_b[8*k+0],
                       (x[8*k+1]-mu)*rs*ln_s[8*k+1]+ln_b[8*k+1]);
            u.y = pk2c((x[8*k+2]-mu)*rs*ln_s[8*k+2]+ln_b[8*k+2],
                       (x[8*k+3]-mu)*rs*ln_s[8*k+3]+ln_b[8*k+3]);
            u.z = pk2c((x[8*k+4]-mu)*rs*ln_s[8*k+4]+ln_b[8*k+4],
                       (x[8*k+5]-mu)*rs*ln_s[8*k+5]+ln_b[8*k+5]);
            u.w = pk2c((x[8*k+6]-mu)*rs*ln_s[8*k+6]+ln_b[8*k+6],
                       (x[8*k+7]-mu)*rs*ln_s[8*k+7]+ln_b[8*k+7]);
            *(uint4*)&KX[qkOff(t, k)] = u;
        }
    }
    // no barrier: wave-private rows; DS pipe is in-order per wave

    // ---- Phase 2: MFMA projections. Gate deferred to epilogue. ----
    const unsigned short* wp = wprep + ((size_t)h * 128 + l) * 8;
    bf16x8 wfQ[2], wfK[2], wfV[2];
#pragma unroll
    for (int ct = 0; ct < 2; ++ct) {
        wfQ[ct] = *(const bf16x8*)&wp[(0 * 1024 + ct * 64) * 8];
        wfK[ct] = *(const bf16x8*)&wp[(1 * 1024 + ct * 64) * 8];
        wfV[ct] = *(const bf16x8*)&wp[(2 * 1024 + ct * 64) * 8];
    }
    bf16x8 Xb[4];                                 // retained for epilogue gate
#pragma unroll
    for (int it = 0; it < 4; ++it)
        Xb[it] = *(const bf16x8*)&KX[qkOff(ibase + it * 16 + lm, lq)];
    // KX (X) now dead for this wave -> reuse rows for Q^T

    // Q^T rows [i][c]  (D[c][i]: lane lm = i, regs = 4 consecutive c)
#pragma unroll
    for (int it = 0; it < 4; ++it)
#pragma unroll
        for (int ct = 0; ct < 2; ++ct) {
            floatx4 d = __builtin_amdgcn_mfma_f32_16x16x32_bf16(wfQ[ct], Xb[it], zero, 0, 0, 0);
            uint2 u; u.x = pk2c(d[0], d[1]); u.y = pk2c(d[2], d[3]);
            int row = ibase + it * 16 + lm;
            *(uint2*)&KX[qkOff(row, 2 * ct + (lq >> 1)) + (lq & 1) * 4] = u;
        }
    // Hoist own Q^T B-frags BEFORE K overwrites the same rows
    bf16x8 Qb[4];
#pragma unroll
    for (int it = 0; it < 4; ++it)
        Qb[it] = *(const bf16x8*)&KX[qkOff(ibase + it * 16 + lm, lq)];

    // K rows [j][c] -> KX (overwrite Q^T; own rows, in-order DS pipe)
#pragma unroll
    for (int it = 0; it < 4; ++it)
#pragma unroll
        for (int ct = 0; ct < 2; ++ct) {
            floatx4 d = __builtin_amdgcn_mfma_f32_16x16x32_bf16(wfK[ct], Xb[it], zero, 0, 0, 0);
            uint2 u; u.x = pk2c(d[0], d[1]); u.y = pk2c(d[2], d[3]);
            int row = ibase + it * 16 + lm;
            *(uint2*)&KX[qkOff(row, 2 * ct + (lq >> 1)) + (lq & 1) * 4] = u;
        }

    // V -> Vt [c][j]  (D[j][c']: lane lm = c', regs = 4 consecutive j)
#pragma unroll
    for (int jt = 0; jt < 4; ++jt)
#pragma unroll
        for (int ct = 0; ct < 2; ++ct) {
            floatx4 d = __builtin_amdgcn_mfma_f32_16x16x32_bf16(Xb[jt], wfV[ct], zero, 0, 0, 0);
            uint2 u; u.x = pk2c(d[0], d[1]); u.y = pk2c(d[2], d[3]);
            int c = ct * 16 + lm;
            int chunk = 8 * w + 2 * jt + (lq >> 1);
            *(uint2*)&Vt[vOff(c, chunk) + (lq & 1) * 4] = u;
        }

    __syncthreads();   // KX (K) / Vt visible to all waves (the only barrier)

    floatx4 accO[2][4];
#pragma unroll
    for (int ct = 0; ct < 2; ++ct)
#pragma unroll
        for (int it = 0; it < 4; ++it) accO[ct][it] = zero;
    float accLv[4] = {0.f, 0.f, 0.f, 0.f};        // denominator, VALU (lane = i)

    const float* bptr = bias32 + (size_t)h * 65536 + w * 2048 + l * 4;

    // ---- Phase 3: j-loop, 32 j/iter; C prefetch + A/B phase split (R7) ----
    for (int jc = 0; jc < 8; ++jc) {
        const float* bj = bptr + jc * 8192;

        // hoisted bias C-loads: 8 x b128 issued back-to-back
        floatx4 Cre[4][2];
#pragma unroll
        for (int it = 0; it < 4; ++it) {
            Cre[it][0] = *(const floatx4*)(bj + it * 256);
            Cre[it][1] = *(const floatx4*)(bj + (4 + it) * 256);
        }
        bf16x8 Ka0 = *(const bf16x8*)&KX[qkOff(jc * 32 + lm, lq)];
        bf16x8 Ka1 = *(const bf16x8*)&KX[qkOff(jc * 32 + 16 + lm, lq)];
        bf16x8 Va0 = *(const bf16x8*)&Vt[vOff(lm, 4 * jc + lq)];
        bf16x8 Va1 = *(const bf16x8*)&Vt[vOff(16 + lm, 4 * jc + lq)];

        // Phase A: QK + exp2 + pack + slab-write, all 4 its
#pragma unroll
        for (int it = 0; it < 4; ++it) {
            const int pb = pwb + it * 512;         // private slab per (wave,it)
            floatx4 S0 = __builtin_amdgcn_mfma_f32_16x16x32_bf16(Ka0, Qb[it], Cre[it][0], 0, 0, 0);
            floatx4 S1 = __builtin_amdgcn_mfma_f32_16x16x32_bf16(Ka1, Qb[it], Cre[it][1], 0, 0, 0);
            float p0 = fexp2(S0[0]), p1 = fexp2(S0[1]);
            float p2 = fexp2(S0[2]), p3 = fexp2(S0[3]);
            float p4 = fexp2(S1[0]), p5 = fexp2(S1[1]);
            float p6 = fexp2(S1[2]), p7 = fexp2(S1[3]);
            accLv[it] += ((p0 + p1) + (p2 + p3)) + ((p4 + p5) + (p6 + p7));
            uint2 u0; u0.x = pk2c(p0, p1); u0.y = pk2c(p2, p3);
            uint2 u1; u1.x = pk2c(p4, p5); u1.y = pk2c(p6, p7);
            // j = 16*jt + 4*lq + r -> chunk = 2*jt + (lq>>1), off (lq&1)*4
            *(uint2*)&Pbuf[pOff(pb, lm, 0 + (lq >> 1)) + (lq & 1) * 4] = u0;
            *(uint2*)&Pbuf[pOff(pb, lm, 2 + (lq >> 1)) + (lq & 1) * 4] = u1;
        }

        // Phase B: batched slab-reads, then PV MFMAs
        bf16x8 Pb0 = *(const bf16x8*)&Pbuf[pOff(pwb + 0 * 512, lm, lq)];
        bf16x8 Pb1 = *(const bf16x8*)&Pbuf[pOff(pwb + 1 * 512, lm, lq)];
        bf16x8 Pb2 = *(const bf16x8*)&Pbuf[pOff(pwb + 2 * 512, lm, lq)];
        bf16x8 Pb3 = *(const bf16x8*)&Pbuf[pOff(pwb + 3 * 512, lm, lq)];
        accO[0][0] = __builtin_amdgcn_mfma_f32_16x16x32_bf16(Va0, Pb0, accO[0][0], 0, 0, 0);
        accO[1][0] = __builtin_amdgcn_mfma_f32_16x16x32_bf16(Va1, Pb0, accO[1][0], 0, 0, 0);
        accO[0][1] = __builtin_amdgcn_mfma_f32_16x16x32_bf16(Va0, Pb1, accO[0][1], 0, 0, 0);
        accO[1][1] = __builtin_amdgcn_mfma_f32_16x16x32_bf16(Va1, Pb1, accO[1][1], 0, 0, 0);
        accO[0][2] = __builtin_amdgcn_mfma_f32_16x16x32_bf16(Va0, Pb2, accO[0][2], 0, 0, 0);
        accO[1][2] = __builtin_amdgcn_mfma_f32_16x16x32_bf16(Va1, Pb2, accO[1][2], 0, 0, 0);
        accO[0][3] = __builtin_amdgcn_mfma_f32_16x16x32_bf16(Va0, Pb3, accO[0][3], 0, 0, 0);
        accO[1][3] = __builtin_amdgcn_mfma_f32_16x16x32_bf16(Va1, Pb3, accO[1][3], 0, 0, 0);
    }

    // ---- Epilogue: reduce L over lq, gate from retained Xb, store ----
    // accO / gate orientation: lane lm = i, regs = c' (4*lq + r per ct).
    // Frag-linear store (R9): frag = (globalrow>>4)*8 + h,
    // offset = (ct*2 + (lq>>1))*128 + lm*8 + (lq&1)*4 shorts.
    {
        bf16x8 wfG0 = *(const bf16x8*)&wp[(3 * 1024 + 0 * 64) * 8];
        bf16x8 wfG1 = *(const bf16x8*)&wp[(3 * 1024 + 1 * 64) * 8];
#pragma unroll
        for (int it = 0; it < 4; ++it) {
            float L = accLv[it];
            L += __shfl_xor(L, 16, 64);
            L += __shfl_xor(L, 32, 64);
            const float inv = frcp(L);               // L[i = ibase + it*16 + lm]
            floatx4 d0 = __builtin_amdgcn_mfma_f32_16x16x32_bf16(wfG0, Xb[it], zero, 0, 0, 0);
            floatx4 d1 = __builtin_amdgcn_mfma_f32_16x16x32_bf16(wfG1, Xb[it], zero, 0, 0, 0);
            const int tile16 = s * 16 + (w * 4 + it);   // globalrow >> 4
            unsigned short* ab = attn16 + ((size_t)(tile16 * 8 + h)) * 512;
            const int lo = lm * 8 + (lq & 1) * 4;
            {
                float o0 = accO[0][it][0] * inv * frcp(1.0f + fexp2(-d0[0]));
                float o1 = accO[0][it][1] * inv * frcp(1.0f + fexp2(-d0[1]));
                float o2 = accO[0][it][2] * inv * frcp(1.0f + fexp2(-d0[2]));
                float o3 = accO[0][it][3] * inv * frcp(1.0f + fexp2(-d0[3]));
                uint2 u; u.x = pk2c(o0, o1); u.y = pk2c(o2, o3);
                *(uint2*)&ab[(0 + (lq >> 1)) * 128 + lo] = u;
            }
            {
                float o0 = accO[1][it][0] * inv * frcp(1.0f + fexp2(-d1[0]));
                float o1 = accO[1][it][1] * inv * frcp(1.0f + fexp2(-d1[1]));
                float o2 = accO[1][it][2] * inv * frcp(1.0f + fexp2(-d1[2]));
                float o3 = accO[1][it][3] * inv * frcp(1.0f + fexp2(-d1[3]));
                uint2 u; u.x = pk2c(o0, o1); u.y = pk2c(o2, o3);
                *(uint2*)&ab[(2 + (lq >> 1)) * 128 + lo] = u;
            }
        }
    }
}

// ---------------------------------------------------------------------------
// Kernel 3: MFMA output projection. out = attn16(frag-linear) @ wo(256x32)+bo
// A-loads are 1KB fully-coalesced frag reads (frag = tile16*8 + kt).
// ---------------------------------------------------------------------------
__global__ __launch_bounds__(256) void proj_kernel(
    const unsigned short* __restrict__ attn16,
    const unsigned short* __restrict__ wofrag,
    const float* __restrict__ bo, float* __restrict__ out)
{
    const int t = threadIdx.x;
    const int l = t & 63, w = t >> 6;
    const int lm = l & 15, lq = l >> 4;
    const int row0 = blockIdx.x * 128 + w * 32;
    const int t16 = row0 >> 4;                   // even tile16 index
    const floatx4 zero = {0.f, 0.f, 0.f, 0.f};

    floatx4 acc[2][2];
#pragma unroll
    for (int it = 0; it < 2; ++it)
#pragma unroll
        for (int nt = 0; nt < 2; ++nt) acc[it][nt] = zero;

#pragma unroll 2
    for (int kt = 0; kt < 8; ++kt) {
        bf16x8 a0 = *(const bf16x8*)&attn16[((size_t)((t16 + 0) * 8 + kt)) * 512 + l * 8];
        bf16x8 a1 = *(const bf16x8*)&attn16[((size_t)((t16 + 1) * 8 + kt)) * 512 + l * 8];
        bf16x8 b0 = *(const bf16x8*)&wofrag[((kt * 2 + 0) * 64 + l) * 8];
        bf16x8 b1 = *(const bf16x8*)&wofrag[((kt * 2 + 1) * 64 + l) * 8];
        acc[0][0] = __builtin_amdgcn_mfma_f32_16x16x32_bf16(a0, b0, acc[0][0], 0, 0, 0);
        acc[0][1] = __builtin_amdgcn_mfma_f32_16x16x32_bf16(a0, b1, acc[0][1], 0, 0, 0);
        acc[1][0] = __builtin_amdgcn_mfma_f32_16x16x32_bf16(a1, b0, acc[1][0], 0, 0, 0);
        acc[1][1] = __builtin_amdgcn_mfma_f32_16x16x32_bf16(a1, b1, acc[1][1], 0, 0, 0);
    }

    float bov[2] = {bo[lm], bo[16 + lm]};
#pragma unroll
    for (int it = 0; it < 2; ++it)
#pragma unroll
        for (int nt = 0; nt < 2; ++nt)
#pragma unroll
            for (int r = 0; r < 4; ++r)
                out[(size_t)(row0 + it * 16 + lq * 4 + r) * NC + nt * 16 + lm]
                    = acc[it][nt][r] + bov[nt];
}

// ---------------------------------------------------------------------------
extern "C" void kernel_launch(void* const* d_in, const int* in_sizes, int n_in,
                              void* d_out, int out_size, void* d_ws, size_t ws_size,
                              hipStream_t stream) {
    const float* m     = (const float*)d_in[0];
    const float* z     = (const float*)d_in[1];
    const float* ln_s  = (const float*)d_in[2];
    const float* ln_b  = (const float*)d_in[3];
    const float* lnb_s = (const float*)d_in[4];
    const float* lnb_b = (const float*)d_in[5];
    const float* wq    = (const float*)d_in[6];
    const float* wk    = (const float*)d_in[7];
    const float* wv    = (const float*)d_in[8];
    const float* wb    = (const float*)d_in[9];
    const float* wg    = (const float*)d_in[10];
    const float* wo    = (const float*)d_in[11];
    const float* bo    = (const float*)d_in[12];
    float* out = (float*)d_out;

    // ws: bias32 2 MB | wprep 64 KB | wofrag 16 KB | attn16 16.78 MB
    float* bias32 = (float*)d_ws;
    unsigned short* wprep  = (unsigned short*)((char*)d_ws + (2u << 20));
    unsigned short* wofrag = (unsigned short*)((char*)d_ws + (2u << 20) + 65536);
    unsigned short* attn16 = (unsigned short*)((char*)d_ws + (2u << 20) + 65536 + 16384);

    biasprep_kernel<<<276, 256, 0, stream>>>(z, lnb_s, lnb_b, wb, wq, wk, wv, wg,
                                             wo, bias32, wprep, wofrag);
    attn_kernel<<<NS * NH, 256, 0, stream>>>(m, ln_s, ln_b, wprep, bias32, attn16);
    proj_kernel<<<(NS * NI) / 128, 256, 0, stream>>>(attn16, wofrag, bo, out);
}